// Round 15
// baseline (284.817 us; speedup 1.0000x reference)
//
#include <hip/hip_runtime.h>
#include <math.h>

#define D_   512
#define H_   8
#define DK_  64
#define FF_  2048
#define S_   2048
#define B_   4
#define M_   (B_*S_)     // 8192
#define EPS_ 1e-5f
#define SCLQ 0.1803368801111f   // 0.125 * log2(e): folded into wq/bq at prep

typedef __attribute__((ext_vector_type(8))) short bf16x8;
typedef __attribute__((ext_vector_type(4))) float f32x4;
typedef __attribute__((ext_vector_type(4))) unsigned int u32x4;

__device__ inline unsigned short f2b(float f) {
    unsigned u = __builtin_bit_cast(unsigned, f);
    unsigned r = (u + 0x7FFFu + ((u >> 16) & 1u)) >> 16;
    return (unsigned short)r;
}
__device__ inline float b2f(unsigned short u) {
    return __builtin_bit_cast(float, (unsigned)u << 16);
}
// pack hi16(p0) low half, hi16(p1) high half (truncating bf16 pair)
__device__ inline unsigned packbf(float p0, float p1) {
    return (__builtin_bit_cast(unsigned, p1) & 0xFFFF0000u) |
           (__builtin_bit_cast(unsigned, p0) >> 16);
}

// async 16B global->LDS. LDS dest must be wave-uniform base + lane*16.
__device__ __forceinline__ void async_cp16(const void* g, void* l) {
    __builtin_amdgcn_global_load_lds(
        (const __attribute__((address_space(1))) unsigned int*)g,
        (__attribute__((address_space(3))) unsigned int*)l, 16, 0, 0);
}

// ---------------------------------------------------------------------------
// Unified preprocessing (1 dispatch, 5120 blocks).
// ---------------------------------------------------------------------------
__global__ __launch_bounds__(256)
void prep_kernel(const float* __restrict__ x,
                 const float* __restrict__ wq, const float* __restrict__ wk,
                 const float* __restrict__ wv, const float* __restrict__ wo,
                 const float* __restrict__ bq, const float* __restrict__ bk,
                 const float* __restrict__ bv,
                 const float* __restrict__ w1, const float* __restrict__ w2,
                 unsigned short* __restrict__ xb, unsigned short* __restrict__ wqkvt,
                 unsigned short* __restrict__ wot, unsigned short* __restrict__ w1t,
                 unsigned short* __restrict__ w2t, float* __restrict__ bqkv)
{
    __shared__ float L[32][33];
    const int bid = blockIdx.x;
    const int tid = threadIdx.x;

    if (bid < 2048) {                       // x -> xb
        const int i = (bid * 256 + tid) * 8;
        const float4 a = *(const float4*)(x + i);
        const float4 b = *(const float4*)(x + i + 4);
        bf16x8 v;
        v[0] = (short)f2b(a.x); v[1] = (short)f2b(a.y);
        v[2] = (short)f2b(a.z); v[3] = (short)f2b(a.w);
        v[4] = (short)f2b(b.x); v[5] = (short)f2b(b.y);
        v[6] = (short)f2b(b.z); v[7] = (short)f2b(b.w);
        *(bf16x8*)(xb + i) = v;
        return;
    }

    const float* w; unsigned short* wt; int K, N, k0, n0; float scl = 1.f;
    if (bid < 3072) {
        const int z = (bid - 2048) >> 8;
        const int r = (bid - 2048) & 255;
        n0 = (r & 15) * 32; k0 = (r >> 4) * 32; K = 512; N = 512;
        w  = (z == 0) ? wq : (z == 1) ? wk : (z == 2) ? wv : wo;
        wt = (z < 3) ? (wqkvt + (size_t)z * 512 * 512) : wot;
        if (z == 0) scl = SCLQ;
        if (z < 3 && r == 0) {
            const float* bsrc = (z == 0) ? bq : (z == 1) ? bk : bv;
            const float bscl  = (z == 0) ? SCLQ : 1.f;
            bqkv[z * 512 + tid]       = bsrc[tid] * bscl;
            bqkv[z * 512 + 256 + tid] = bsrc[256 + tid] * bscl;
        }
    } else if (bid < 4096) {
        const int r = bid - 3072;
        n0 = (r & 63) * 32; k0 = (r >> 6) * 32; K = 512; N = 2048;
        w = w1; wt = w1t;
    } else {
        const int r = bid - 4096;
        n0 = (r & 15) * 32; k0 = (r >> 4) * 32; K = 2048; N = 512;
        w = w2; wt = w2t;
    }

    const int xx = tid & 31, y = tid >> 5;
#pragma unroll
    for (int i = 0; i < 4; i++)
        L[y + i * 8][xx] = w[(size_t)(k0 + y + i * 8) * N + n0 + xx] * scl;
    __syncthreads();
#pragma unroll
    for (int i = 0; i < 4; i++)
        wt[(size_t)(n0 + y + i * 8) * K + k0 + xx] = f2b(L[xx][y + i * 8]);
}

// ---------------------------------------------------------------------------
// bf16 MFMA GEMM, DEPTH-deep prefetch (3 LDS buffers = 2 tiles in flight):
// wait vmcnt((DEPTH-1)*(CA+CB)) — never drains the staging queue (AITER
// pattern: current tile's loads complete while 2 more stream behind).
// RESADD: 0 none, 1 fp32 residual, 2 bf16 residual (C-layout indexed).
// ---------------------------------------------------------------------------
template<int WR, int WC, int MT, int NT, int OUTB, int RELU, int RESADD, int HASBIAS, int DEPTH>
__global__ __launch_bounds__(256)
void gemm_bf16(const unsigned short* __restrict__ A, const unsigned short* __restrict__ Bt,
               const float* __restrict__ bias, const void* __restrict__ RES,
               void* __restrict__ Cv, int K, int lda, int ldb, int ldc)
{
    constexpr int BM = WR * MT * 16;
    constexpr int BN = WC * NT * 16;
    constexpr int CA = BM / 64;
    constexpr int CB = BN / 64;
    __shared__ unsigned short As[DEPTH][BM * 32];
    __shared__ unsigned short Bs[DEPTH][BN * 32];

    const int tid  = threadIdx.x;
    const int lane = tid & 63;
    const int w    = tid >> 6;
    const int wr   = w / WC, wc = w % WC;
    const int quad = lane >> 4;
    const int l15  = lane & 15;
    const int n0   = blockIdx.x * BN;
    const int m0   = blockIdx.y * BM;

    f32x4 acc[MT][NT];
#pragma unroll
    for (int i = 0; i < MT; i++)
#pragma unroll
        for (int j = 0; j < NT; j++) acc[i][j] = (f32x4){0.f, 0.f, 0.f, 0.f};

    auto stage = [&](int k0, int bufi) {
#pragma unroll
        for (int i = 0; i < CA; i++) {
            const int c = tid + i * 256;
            async_cp16(&A[(size_t)(m0 + (c >> 2)) * lda + k0 + (c & 3) * 8], &As[bufi][c * 8]);
        }
#pragma unroll
        for (int i = 0; i < CB; i++) {
            const int c = tid + i * 256;
            async_cp16(&Bt[(size_t)(n0 + (c >> 2)) * ldb + k0 + (c & 3) * 8], &Bs[bufi][c * 8]);
        }
    };

    const int niter = K >> 5;
    stage(0, 0);
    if (DEPTH >= 3) stage(32, 1);           // all our K >= 64
    for (int ii = 0; ii < niter; ii++) {
        const int kn = ii + DEPTH - 1;
        stage(kn < niter ? kn * 32 : 0, kn % DEPTH);
        __builtin_amdgcn_s_waitcnt(0x0f70 | ((DEPTH - 1) * (CA + CB)));
        __builtin_amdgcn_s_barrier();

        const unsigned short* Ac = &As[ii % DEPTH][0];
        const unsigned short* Bc = &Bs[ii % DEPTH][0];
        bf16x8 af[MT], bfr[NT];
#pragma unroll
        for (int t = 0; t < MT; t++)
            af[t]  = *(const bf16x8*)&Ac[(wr * MT * 16 + t * 16 + l15) * 32 + quad * 8];
#pragma unroll
        for (int t = 0; t < NT; t++)
            bfr[t] = *(const bf16x8*)&Bc[(wc * NT * 16 + t * 16 + l15) * 32 + quad * 8];
#pragma unroll
        for (int mt = 0; mt < MT; mt++)
#pragma unroll
            for (int nt = 0; nt < NT; nt++)
                acc[mt][nt] = __builtin_amdgcn_mfma_f32_16x16x32_bf16(
                    af[mt], bfr[nt], acc[mt][nt], 0, 0, 0);
        __builtin_amdgcn_s_barrier();
    }

    // epilogue: C/D layout col=lane&15, row=quad*4+reg
#pragma unroll
    for (int mt = 0; mt < MT; mt++) {
        const int rowb = m0 + wr * MT * 16 + mt * 16 + quad * 4;
#pragma unroll
        for (int nt = 0; nt < NT; nt++) {
            const int col = n0 + wc * NT * 16 + nt * 16 + l15;
            const float bv = HASBIAS ? bias[col] : 0.f;
#pragma unroll
            for (int r = 0; r < 4; r++) {
                const size_t idx = (size_t)(rowb + r) * ldc + col;
                float v = acc[mt][nt][r] + bv;
                if (RESADD == 1) v += ((const float*)RES)[idx];
                if (RESADD == 2) v += b2f(((const unsigned short*)RES)[idx]);
                if (RELU)   v = fmaxf(v, 0.f);
                if (OUTB) ((unsigned short*)Cv)[idx] = f2b(v);
                else      ((float*)Cv)[idx] = v;
            }
        }
    }
}

// ---------------------------------------------------------------------------
// V transpose: qkv v-part [s][dk] per (b,h) -> vt [(b*8+h)*64+dk][s] bf16.
// ---------------------------------------------------------------------------
__global__ __launch_bounds__(256)
void vtrans(const unsigned short* __restrict__ qkv, unsigned short* __restrict__ vt)
{
    __shared__ unsigned short L[64][72];
    const int s0 = blockIdx.x * 64;
    const int bh = blockIdx.y;
    const int b  = bh >> 3, hh = bh & 7;
    const int tid = threadIdx.x;
    const unsigned short* src = qkv + (size_t)(b * S_) * 1536 + 1024 + hh * 64;
#pragma unroll
    for (int i = 0; i < 2; i++) {
        const int c = tid + i * 256;
        const int r = c >> 3, sub = (c & 7) * 8;
        *(bf16x8*)&L[r][sub] = *(const bf16x8*)(src + (size_t)(s0 + r) * 1536 + sub);
    }
    __syncthreads();
    const int dk = tid >> 2;
    const int sc = (tid & 3) * 16;
    bf16x8 t0, t1;
#pragma unroll
    for (int j = 0; j < 8; j++) t0[j] = (short)L[sc + j][dk];
#pragma unroll
    for (int j = 0; j < 8; j++) t1[j] = (short)L[sc + 8 + j][dk];
    unsigned short* dst = vt + (size_t)(bh * 64 + dk) * S_ + s0 + sc;
    *(bf16x8*)(dst)     = t0;
    *(bf16x8*)(dst + 8) = t1;
}

// ---------------------------------------------------------------------------
// Causal flash attention, K-SPLIT register-P (r14 structure — banked win).
// ---------------------------------------------------------------------------
__global__ __launch_bounds__(256, 4)
void attn_mfma(const unsigned short* __restrict__ qkv,
               const unsigned short* __restrict__ vt,
               unsigned short* __restrict__ ctx)
{
    __shared__ unsigned short Ks[2][64 * 64];   // [kr][d], chunk^=(kr&7)
    __shared__ unsigned short Vs[2][64 * 64];   // [dk][kr], chunk^=(dk&7)

    const int tid  = threadIdx.x;
    const int lane = tid & 63;
    const int w    = tid >> 6;
    const int quad = lane >> 4;
    const int l15  = lane & 15;
    const int bid  = blockIdx.x;
    const int qb   = 31 - (bid >> 5);           // LPT: heaviest first
    const int bh   = bid & 31;
    const int b    = bh >> 3, hh = bh & 7;
    const int kh   = w & 1;                     // k-chunk (32 keys)
    const int qh   = w >> 1;                    // q-half (32 queries)

    const unsigned short* qbase = qkv + (size_t)(b * S_) * 1536 + hh * 64;
    const unsigned short* kbase = qbase + 512;
    const unsigned short* vtb   = vt + (size_t)bh * 64 * S_;

    const int srcA  = 32 * (quad & 1) + l15;    // shuffle sources (same q col)
    const int srcB  = srcA + 16;
    const bool selHi = (quad >> 1) != 0;        // target k 16..31 -> tile kt=1

    bf16x8 ones;
#pragma unroll
    for (int j = 0; j < 8; j++) ones[j] = (short)0x3F80;

    auto stage = [&](int kb, int bufi) {
        unsigned short* kd = &Ks[bufi][0];
        unsigned short* vd = &Vs[bufi][0];
#pragma unroll
        for (int i = 0; i < 2; i++) {
            const int c = tid + i * 256;
            const int row = c >> 3;
            const int l = (c & 7) ^ (row & 7);
            async_cp16(kbase + (size_t)(kb * 64 + row) * 1536 + l * 8, kd + c * 8);
            async_cp16(vtb + (size_t)row * S_ + kb * 64 + l * 8, vd + c * 8);
        }
    };

    // Q fragments: 2 q-tiles x 2 kc (d chunks)
    bf16x8 qf[2][2];
#pragma unroll
    for (int qt = 0; qt < 2; qt++) {
        const unsigned short* qr = qbase + (size_t)(qb * 64 + qh * 32 + qt * 16 + l15) * 1536;
        qf[qt][0] = *(const bf16x8*)(qr + quad * 8);
        qf[qt][1] = *(const bf16x8*)(qr + 32 + quad * 8);
    }

    f32x4 Oacc[2][5];                           // [qt][0..3]=O dk-tiles, [4]=row-sum
#pragma unroll
    for (int qt = 0; qt < 2; qt++)
#pragma unroll
        for (int i = 0; i < 5; i++) Oacc[qt][i] = (f32x4){0.f, 0.f, 0.f, 0.f};

    stage(0, 0);

    // assemble PV A-fragment (32-k chunk) from two S^T tiles (kt0, kt1)
    auto assemble2 = [&](const unsigned t0[2], const unsigned t1[2]) -> bf16x8 {
        const unsigned a0A = __shfl(t0[0], srcA, 64);
        const unsigned a1A = __shfl(t0[1], srcA, 64);
        const unsigned b0A = __shfl(t1[0], srcA, 64);
        const unsigned b1A = __shfl(t1[1], srcA, 64);
        const unsigned a0B = __shfl(t0[0], srcB, 64);
        const unsigned a1B = __shfl(t0[1], srcB, 64);
        const unsigned b0B = __shfl(t1[0], srcB, 64);
        const unsigned b1B = __shfl(t1[1], srcB, 64);
        u32x4 a;
        a[0] = selHi ? b0A : a0A;
        a[1] = selHi ? b1A : a1A;
        a[2] = selHi ? b0B : a0B;
        a[3] = selHi ? b1B : a1B;
        return __builtin_bit_cast(bf16x8, a);
    };

    const int physv = (kh * 4 + quad) ^ (l15 & 7);  // V^T k-offset chunk for this wave

    // ---- main loop (kb < qb): no masking
    for (int kb = 0; kb < qb; kb++) {
        stage(kb + 1, (kb + 1) & 1);
        __builtin_amdgcn_s_waitcnt(0x0F74);     // vmcnt(4): current tile done
        __builtin_amdgcn_s_barrier();
        const unsigned short* Kc = &Ks[kb & 1][0];
        const unsigned short* Vc = &Vs[kb & 1][0];

        f32x4 st[2][2];                         // [qt][kt]
#pragma unroll
        for (int qt = 0; qt < 2; qt++)
#pragma unroll
            for (int kt = 0; kt < 2; kt++) st[qt][kt] = (f32x4){0.f, 0.f, 0.f, 0.f};
#pragma unroll
        for (int kc = 0; kc < 2; kc++) {
            const int phys = (kc * 4 + quad) ^ (l15 & 7);
            const bf16x8 kf0 = *(const bf16x8*)&Kc[(kh * 32 + l15) * 64 + phys * 8];
            const bf16x8 kf1 = *(const bf16x8*)&Kc[(kh * 32 + 16 + l15) * 64 + phys * 8];
#pragma unroll
            for (int qt = 0; qt < 2; qt++) {
                st[qt][0] = __builtin_amdgcn_mfma_f32_16x16x32_bf16(kf0, qf[qt][kc], st[qt][0], 0, 0, 0);
                st[qt][1] = __builtin_amdgcn_mfma_f32_16x16x32_bf16(kf1, qf[qt][kc], st[qt][1], 0, 0, 0);
            }
        }

        unsigned pk[2][2][2];                   // [qt][kt][regpair]
#pragma unroll
        for (int qt = 0; qt < 2; qt++)
#pragma unroll
            for (int kt = 0; kt < 2; kt++) {
                pk[qt][kt][0] = packbf(exp2f(st[qt][kt][0]), exp2f(st[qt][kt][1]));
                pk[qt][kt][1] = packbf(exp2f(st[qt][kt][2]), exp2f(st[qt][kt][3]));
            }

        bf16x8 vf[4];
#pragma unroll
        for (int nt = 0; nt < 4; nt++)
            vf[nt] = *(const bf16x8*)&Vc[(nt * 16 + l15) * 64 + physv * 8];
#pragma unroll
        for (int qt = 0; qt < 2; qt++) {
            const bf16x8 af = assemble2(pk[qt][0], pk[qt][1]);
#pragma unroll
            for (int nt = 0; nt < 4; nt++)
                Oacc[qt][nt] = __builtin_amdgcn_mfma_f32_16x16x32_bf16(af, vf[nt], Oacc[qt][nt], 0, 0, 0);
            Oacc[qt][4] = __builtin_amdgcn_mfma_f32_16x16x32_bf16(af, ones, Oacc[qt][4], 0, 0, 0);
        }
        __builtin_amdgcn_s_barrier();           // reads done before re-stage
    }

    // ---- peeled diagonal iteration (kb == qb)
    {
        stage(0, (qb + 1) & 1);                 // dummy prefetch (vmcnt uniform)
        __builtin_amdgcn_s_waitcnt(0x0F74);
        __builtin_amdgcn_s_barrier();
        const unsigned short* Kc = &Ks[qb & 1][0];
        const unsigned short* Vc = &Vs[qb & 1][0];

        const bool skipDiag = (kh == 1 && qh == 0);   // k 32..63 > q 0..31: all masked
        const bool fullDiag = (kh == 0 && qh == 1);   // k 0..31 < q 32..63: no mask

        if (!skipDiag) {
            f32x4 st[2][2];
#pragma unroll
            for (int qt = 0; qt < 2; qt++)
#pragma unroll
                for (int kt = 0; kt < 2; kt++) st[qt][kt] = (f32x4){0.f, 0.f, 0.f, 0.f};
#pragma unroll
            for (int kc = 0; kc < 2; kc++) {
                const int phys = (kc * 4 + quad) ^ (l15 & 7);
                const bf16x8 kf0 = *(const bf16x8*)&Kc[(kh * 32 + l15) * 64 + phys * 8];
                const bf16x8 kf1 = *(const bf16x8*)&Kc[(kh * 32 + 16 + l15) * 64 + phys * 8];
#pragma unroll
                for (int qt = 0; qt < 2; qt++) {
                    st[qt][0] = __builtin_amdgcn_mfma_f32_16x16x32_bf16(kf0, qf[qt][kc], st[qt][0], 0, 0, 0);
                    st[qt][1] = __builtin_amdgcn_mfma_f32_16x16x32_bf16(kf1, qf[qt][kc], st[qt][1], 0, 0, 0);
                }
            }

            unsigned pk[2][2][2];
            if (fullDiag) {
#pragma unroll
                for (int qt = 0; qt < 2; qt++)
#pragma unroll
                    for (int kt = 0; kt < 2; kt++) {
                        pk[qt][kt][0] = packbf(exp2f(st[qt][kt][0]), exp2f(st[qt][kt][1]));
                        pk[qt][kt][1] = packbf(exp2f(st[qt][kt][2]), exp2f(st[qt][kt][3]));
                    }
            } else {
                // tiles: (qt0,kt0) tri, (qt0,kt1) all-masked, (qt1,kt0) full,
                // (qt1,kt1) tri. tri predicate (local): quad*4+r > l15.
                float p[4];
#pragma unroll
                for (int r = 0; r < 4; r++)
                    p[r] = (quad * 4 + r > l15) ? 0.f : exp2f(st[0][0][r]);
                pk[0][0][0] = packbf(p[0], p[1]);
                pk[0][0][1] = packbf(p[2], p[3]);
                pk[0][1][0] = 0u; pk[0][1][1] = 0u;
                pk[1][0][0] = packbf(exp2f(st[1][0][0]), exp2f(st[1][0][1]));
                pk[1][0][1] = packbf(exp2f(st[1][0][2]), exp2f(st[1][0][3]));
#pragma unroll
                for (int r = 0; r < 4; r++)
                    p[r] = (quad * 4 + r > l15) ? 0.f : exp2f(st[1][1][r]);
                pk[1][1][0] = packbf(p[0], p[1]);
                pk[1][1][1] = packbf(p[2], p[3]);
            }

            bf16x8 vf[4];
#pragma unroll
            for (int nt = 0; nt < 4; nt++)
                vf[nt] = *(const bf16x8*)&Vc[(nt * 16 + l15) * 64 + physv * 8];
#pragma unroll
            for (int qt = 0; qt < 2; qt++) {
                const bf16x8 af = assemble2(pk[qt][0], pk[qt][1]);
#pragma unroll
                for (int nt = 0; nt < 4; nt++)
                    Oacc[qt][nt] = __builtin_amdgcn_mfma_f32_16x16x32_bf16(af, vf[nt], Oacc[qt][nt], 0, 0, 0);
                Oacc[qt][4] = __builtin_amdgcn_mfma_f32_16x16x32_bf16(af, ones, Oacc[qt][4], 0, 0, 0);
            }
        }
    }

    // ---- cross-wave reduction (kh=1 partials -> kh=0), then write ctx
    __syncthreads();
    float* red = (float*)&Ks[0][0];             // 2 regions x 64 lanes x 44 floats
    const int rbase = (qh * 64 + lane) * 44;
    if (kh) {
#pragma unroll
        for (int qt = 0; qt < 2; qt++)
#pragma unroll
            for (int i = 0; i < 5; i++)
                *(f32x4*)&red[rbase + (qt * 5 + i) * 4] = Oacc[qt][i];
    }
    __syncthreads();
    if (!kh) {
#pragma unroll
        for (int qt = 0; qt < 2; qt++)
#pragma unroll
            for (int i = 0; i < 5; i++)
                Oacc[qt][i] += *(const f32x4*)&red[rbase + (qt * 5 + i) * 4];

        unsigned short* cb = ctx + (size_t)(b * S_) * 512 + hh * 64;
#pragma unroll
        for (int qt = 0; qt < 2; qt++) {
            const int orow = qb * 64 + qh * 32 + qt * 16 + quad * 4;
#pragma unroll
            for (int r = 0; r < 4; r++) {
                const float inv = 1.f / Oacc[qt][4][r];
#pragma unroll
                for (int nt = 0; nt < 4; nt++)
                    cb[(size_t)(orow + r) * 512 + nt * 16 + l15] = f2b(Oacc[qt][nt][r] * inv);
            }
        }
    }
}

// ---------------------------------------------------------------------------
// LayerNorm: WF -> fp32 out, WB -> bf16 out. 1 wave/row.
// ---------------------------------------------------------------------------
template<int WF, int WB>
__global__ __launch_bounds__(256)
void ln_kernel(const float* __restrict__ s, const float* __restrict__ g,
               const float* __restrict__ be, float* __restrict__ out,
               unsigned short* __restrict__ outb)
{
    const int wave = threadIdx.x >> 6;
    const int lane = threadIdx.x & 63;
    const int row  = blockIdx.x * 4 + wave;
    const float* ps = s + (size_t)row * D_;
    const int c0 = lane * 4;

    float v[8];
    {
        const float4 a0 = *(const float4*)(ps + c0);
        const float4 a1 = *(const float4*)(ps + c0 + 256);
        v[0] = a0.x; v[1] = a0.y; v[2] = a0.z; v[3] = a0.w;
        v[4] = a1.x; v[5] = a1.y; v[6] = a1.z; v[7] = a1.w;
    }

    float sum = 0.f;
#pragma unroll
    for (int i = 0; i < 8; i++) sum += v[i];
#pragma unroll
    for (int m = 1; m < 64; m <<= 1) sum += __shfl_xor(sum, m);
    const float mu = sum * (1.f / D_);

    float sq = 0.f;
#pragma unroll
    for (int i = 0; i < 8; i++) { const float d = v[i] - mu; sq += d * d; }
#pragma unroll
    for (int m = 1; m < 64; m <<= 1) sq += __shfl_xor(sq, m);
    const float rstd = rsqrtf(sq * (1.f / D_) + EPS_);

    const float4 g0 = *(const float4*)(g + c0);
    const float4 b0 = *(const float4*)(be + c0);
    const float4 g1 = *(const float4*)(g + c0 + 256);
    const float4 b1 = *(const float4*)(be + c0 + 256);

    float o[8];
    o[0] = (v[0] - mu) * rstd * g0.x + b0.x;
    o[1] = (v[1] - mu) * rstd * g0.y + b0.y;
    o[2] = (v[2] - mu) * rstd * g0.z + b0.z;
    o[3] = (v[3] - mu) * rstd * g0.w + b0.w;
    o[4] = (v[4] - mu) * rstd * g1.x + b1.x;
    o[5] = (v[5] - mu) * rstd * g1.y + b1.y;
    o[6] = (v[6] - mu) * rstd * g1.z + b1.z;
    o[7] = (v[7] - mu) * rstd * g1.w + b1.w;

    if (WF) {
        *(float4*)(out + (size_t)row * D_ + c0)       = *(float4*)&o[0];
        *(float4*)(out + (size_t)row * D_ + c0 + 256) = *(float4*)&o[4];
    }
    if (WB) {
        short4 vb0 = (short4){(short)f2b(o[0]), (short)f2b(o[1]), (short)f2b(o[2]), (short)f2b(o[3])};
        short4 vb1 = (short4){(short)f2b(o[4]), (short)f2b(o[5]), (short)f2b(o[6]), (short)f2b(o[7])};
        *(short4*)(outb + (size_t)row * D_ + c0)       = vb0;
        *(short4*)(outb + (size_t)row * D_ + c0 + 256) = vb1;
    }
}

// ---------------------------------------------------------------------------
extern "C" void kernel_launch(void* const* d_in, const int* in_sizes, int n_in,
                              void* d_out, int out_size, void* d_ws, size_t ws_size,
                              hipStream_t stream)
{
    const float* x  = (const float*)d_in[0];
    const float* wq = (const float*)d_in[2];
    const float* bq = (const float*)d_in[3];
    const float* wk = (const float*)d_in[4];
    const float* bk = (const float*)d_in[5];
    const float* wv = (const float*)d_in[6];
    const float* bv = (const float*)d_in[7];
    const float* wo = (const float*)d_in[8];
    const float* bo = (const float*)d_in[9];
    const float* w1 = (const float*)d_in[10];
    const float* b1 = (const float*)d_in[11];
    const float* w2 = (const float*)d_in[12];
    const float* b2 = (const float*)d_in[13];
    const float* g1 = (const float*)d_in[14];
    const float* be1= (const float*)d_in[15];
    const float* g2 = (const float*)d_in[16];
    const float* be2= (const float*)d_in[17];
    float* out = (float*)d_out;

    const size_t MB = 1048576;
    char* w8 = (char*)d_ws;
    unsigned short* wqkvt = (unsigned short*)(w8 + 0);            // 1536x512 bf16
    unsigned short* wot   = (unsigned short*)(w8 + 1572864);      // 512x512
    unsigned short* w1t   = (unsigned short*)(w8 + 2097152);      // 2048x512
    unsigned short* w2t   = (unsigned short*)(w8 + 4194304);      // 512x2048
    float*          bqkv  = (float*)(w8 + 6291456);               // 1536 f32
    unsigned short* qkv   = (unsigned short*)(w8 + 8 * MB);       // 24 MB (later ffn1b)
    unsigned short* ffn1b = qkv;
    unsigned short* xb    = (unsigned short*)(w8 + 40 * MB);      // 8 MB (later ctx)
    unsigned short* ctx   = xb;
    unsigned short* vt    = (unsigned short*)(w8 + 48 * MB);      // 8 MB (later hb)
    unsigned short* hb    = vt;
    float*          pre   = (float*)(w8 + 56 * MB);               // 16 MB

    const dim3 blk(256);

    // unified preprocessing (1 dispatch)
    prep_kernel<<<dim3(5120), blk, 0, stream>>>(
        x, wq, wk, wv, wo, bq, bk, bv, w1, w2, xb, wqkvt, wot, w1t, w2t, bqkv);

    // qkv = xb @ [wq*SCLQ|wk|wv] + b -> bf16 [M][1536]   (depth-2 prefetch)
    gemm_bf16<2,2,4,4,1,0,0,1,3><<<dim3(12, 64), blk, 0, stream>>>(
        xb, wqkvt, bqkv, nullptr, qkv, 512, 512, 512, 1536);

    vtrans<<<dim3(32, 32), blk, 0, stream>>>(qkv, vt);

    // causal flash attention (k-split register-P, 1024-block LPT) -> ctx bf16
    attn_mfma<<<dim3(1024), blk, 0, stream>>>(qkv, vt, ctx);

    // pre = x + ctx @ wo + bo (fp32 residual)   (depth-2 prefetch)
    gemm_bf16<2,2,2,4,0,0,1,1,3><<<dim3(4, 128), blk, 0, stream>>>(
        ctx, wot, bo, x, pre, 512, 512, 512, 512);

    // hb = LN(pre) bf16 only
    ln_kernel<0,1><<<dim3(M_ / 4), blk, 0, stream>>>(pre, g1, be1, nullptr, hb);

    // ffn1 = relu(hb @ w1 + b1) -> bf16 [M][2048]   (depth-2 prefetch)
    gemm_bf16<2,2,4,4,1,1,0,1,3><<<dim3(16, 64), blk, 0, stream>>>(
        hb, w1t, b1, nullptr, ffn1b, 512, 512, 512, 2048);

    // pre = hb + ffn1 @ w2 + b2 (bf16 residual)   (depth-2 prefetch)
    gemm_bf16<2,2,2,4,0,0,2,1,3><<<dim3(4, 128), blk, 0, stream>>>(
        ffn1b, w2t, b2, hb, pre, 2048, 2048, 2048, 512);

    // out = LN(pre)
    ln_kernel<1,0><<<dim3(M_ / 4), blk, 0, stream>>>(pre, g2, be2, out, nullptr);
}